// Round 2
// baseline (667.277 us; speedup 1.0000x reference)
//
#include <hip/hip_runtime.h>
#include <hip/hip_bf16.h>

// NetVLAD on gfx950.
// Pipeline: prep (w,b) -> assign (norm+logits fp32+softmax -> a bf16) ->
//           vlad GEMM (bf16 MFMA, split-K partials) -> finalize (norms).
// ws layout (bytes): [0,32K) wT | [32K,33K) b | [1M,3M) invn f32 |
//                    [4M,68M) a bf16 | [68M,100M) partials f32 | [100M,+256K) asum
// Requires ws_size >= ~101 MB.

#define NIMG 32
#define C 128
#define S 16384
#define K 64
#define SPLITS 32
#define SPAN (S / SPLITS)   // 512 pixels per split block
#define CHUNK 32
#define PAD 40              // LDS row stride (bf16 elems): 80 B, 16B-aligned, ~2-way banks

typedef short bf16x8 __attribute__((ext_vector_type(8)));
typedef float f32x4 __attribute__((ext_vector_type(4)));

__device__ __forceinline__ unsigned short f2bf(float f) {
    union { __hip_bfloat16 h; unsigned short u; } v;
    v.h = __float2bfloat16(f);
    return v.u;
}

__global__ __launch_bounds__(256) void k_prep(const float* __restrict__ cent,
                                              float* __restrict__ wT,
                                              float* __restrict__ bvec) {
    int t = threadIdx.x;
    for (int idx = t; idx < C * K; idx += 256) {
        int c = idx >> 6, k = idx & 63;
        wT[idx] = 200.0f * cent[k * C + c];   // wT[c][k]
    }
    if (t < K) {
        float ss = 0.f;
        for (int c = 0; c < C; ++c) { float v = cent[t * C + c]; ss += v * v; }
        bvec[t] = -100.0f * sqrtf(ss);
    }
}

// One thread per pixel; 64 logits in VGPRs; w via wave-uniform loads (s_load).
__global__ __launch_bounds__(256) void k_assign(const float* __restrict__ x,
                                                const float* __restrict__ wT,
                                                const float* __restrict__ bvec,
                                                float* __restrict__ invn_ws,
                                                unsigned short* __restrict__ a_ws) {
    int n = blockIdx.x >> 6;          // 64 tiles of 256 pixels per image
    int tile = blockIdx.x & 63;
    int s = tile * 256 + threadIdx.x;
    const float* xp = x + (size_t)n * C * S + s;

    // Phase A: channel sum-of-squares (coalesced: lanes = consecutive s)
    float ss = 0.f;
    for (int c = 0; c < C; ++c) { float v = xp[(size_t)c * S]; ss += v * v; }
    float nrm = sqrtf(ss);
    float inv = 1.0f / fmaxf(nrm, 1e-12f);
    invn_ws[n * S + s] = inv;

    // Phase B: logits (fp32). w loads are wave-uniform -> scalar path.
    float lg[K];
#pragma unroll
    for (int k = 0; k < K; ++k) lg[k] = bvec[k];
    for (int c = 0; c < C; ++c) {
        float xnc = xp[(size_t)c * S] * inv;    // L2/L3-resident re-read
        const float4* wrow = (const float4*)(wT + c * K);
#pragma unroll
        for (int k4 = 0; k4 < K / 4; ++k4) {
            float4 w = wrow[k4];
            lg[4 * k4 + 0] = fmaf(w.x, xnc, lg[4 * k4 + 0]);
            lg[4 * k4 + 1] = fmaf(w.y, xnc, lg[4 * k4 + 1]);
            lg[4 * k4 + 2] = fmaf(w.z, xnc, lg[4 * k4 + 2]);
            lg[4 * k4 + 3] = fmaf(w.w, xnc, lg[4 * k4 + 3]);
        }
    }

    // Softmax over K in registers
    float m = lg[0];
#pragma unroll
    for (int k = 1; k < K; ++k) m = fmaxf(m, lg[k]);
    float sum = 0.f;
#pragma unroll
    for (int k = 0; k < K; ++k) { lg[k] = __expf(lg[k] - m); sum += lg[k]; }
    float rs = 1.0f / sum;

    unsigned short* ap = a_ws + (size_t)n * K * S + s;
#pragma unroll
    for (int k = 0; k < K; ++k) ap[(size_t)k * S] = f2bf(lg[k] * rs);
}

// VLAD GEMM: out[k][c] (+ asum col) = sum_s a_bf16[k,s] * xn_bf16[c,s].
// Block = image n, s-split of 512; 4 waves, wave w owns k-rows [16w,16w+16).
__global__ __launch_bounds__(256) void k_vlad(const float* __restrict__ x,
                                              const float* __restrict__ invn_ws,
                                              const unsigned short* __restrict__ a_ws,
                                              float* __restrict__ part,
                                              float* __restrict__ asum_p) {
    __shared__ unsigned short a_lds[K * PAD];   // 64 x 40 bf16
    __shared__ unsigned short x_lds[C * PAD];   // 128 x 40 bf16

    int n = blockIdx.x >> 5;
    int sp = blockIdx.x & 31;
    int s_base = sp * SPAN;
    int t = threadIdx.x, l = t & 63, w = t >> 6;
    int kw = 16 * w;
    int l15 = l & 15, lhi = l >> 4;

    f32x4 acc[8];
    f32x4 accS;
#pragma unroll
    for (int i = 0; i < 8; ++i) acc[i] = (f32x4){0.f, 0.f, 0.f, 0.f};
    accS = (f32x4){0.f, 0.f, 0.f, 0.f};

    bf16x8 ones;
#pragma unroll
    for (int i = 0; i < 8; ++i) ones[i] = (short)0x3F80;   // bf16(1.0)

    for (int ch = 0; ch < SPAN / CHUNK; ++ch) {
        int s0 = s_base + ch * CHUNK;
        __syncthreads();   // protect LDS from prev-iter fragment reads
        {   // stage a: row k = t>>2, 8 s per thread
            int k = t >> 2, soff = (t & 3) * 8;
            uint4 v = *(const uint4*)(a_ws + (size_t)n * K * S + (size_t)k * S + s0 + soff);
            *(uint4*)(&a_lds[k * PAD + soff]) = v;
        }
        {   // stage x: row c = t>>1, 16 s per thread, *invn -> bf16
            int c = t >> 1, half = t & 1;
            const float4* xsrc = (const float4*)(x + (size_t)n * C * S + (size_t)c * S + s0 + 16 * half);
            const float4* isrc = (const float4*)(invn_ws + n * S + s0 + 16 * half);
            unsigned int uu[8];
#pragma unroll
            for (int q = 0; q < 4; ++q) {
                float4 xv = xsrc[q];
                float4 iv = isrc[q];
                unsigned short b0 = f2bf(xv.x * iv.x), b1 = f2bf(xv.y * iv.y);
                unsigned short b2 = f2bf(xv.z * iv.z), b3 = f2bf(xv.w * iv.w);
                uu[2 * q]     = (unsigned int)b0 | ((unsigned int)b1 << 16);
                uu[2 * q + 1] = (unsigned int)b2 | ((unsigned int)b3 << 16);
            }
            uint4 w0 = {uu[0], uu[1], uu[2], uu[3]};
            uint4 w1 = {uu[4], uu[5], uu[6], uu[7]};
            *(uint4*)(&x_lds[c * PAD + 16 * half])     = w0;
            *(uint4*)(&x_lds[c * PAD + 16 * half + 8]) = w1;
        }
        __syncthreads();

        // A fragment: row = kw + (l&15), k-elems s = 8*(l>>4)+i
        bf16x8 af = *(const bf16x8*)(&a_lds[(kw + l15) * PAD + 8 * lhi]);
#pragma unroll
        for (int nt = 0; nt < 8; ++nt) {
            bf16x8 bfv = *(const bf16x8*)(&x_lds[(16 * nt + l15) * PAD + 8 * lhi]);
            acc[nt] = __builtin_amdgcn_mfma_f32_16x16x32_bf16(af, bfv, acc[nt], 0, 0, 0);
        }
        accS = __builtin_amdgcn_mfma_f32_16x16x32_bf16(af, ones, accS, 0, 0, 0);
    }

    // Write fp32 partials. D: col = l&15 (+16*nt), row = kw + 4*(l>>4) + j.
    size_t pbase = (size_t)(n * SPLITS + sp) * K * C;
#pragma unroll
    for (int nt = 0; nt < 8; ++nt) {
#pragma unroll
        for (int j = 0; j < 4; ++j) {
            int row = kw + 4 * lhi + j;
            int col = 16 * nt + l15;
            part[pbase + (size_t)row * C + col] = acc[nt][j];
        }
    }
    if (l15 == 0) {
        int rb = kw + 4 * lhi;
#pragma unroll
        for (int j = 0; j < 4; ++j)
            asum_p[(size_t)(n * SPLITS + sp) * K + rb + j] = accS[j];
    }
}

__global__ __launch_bounds__(256) void k_final(const float* __restrict__ part,
                                               const float* __restrict__ asum_p,
                                               const float* __restrict__ cent,
                                               float* __restrict__ out) {
    __shared__ float vlad[K * C];
    __shared__ float rinv_l[K];
    __shared__ float ssn[K];
    __shared__ float asum_l[K];
    __shared__ float ginv_s;
    int n = blockIdx.x, t = threadIdx.x;

    if (t < K) {
        float s = 0.f;
        for (int sp = 0; sp < SPLITS; ++sp) s += asum_p[(size_t)(n * SPLITS + sp) * K + t];
        asum_l[t] = s;
    }
    __syncthreads();
    for (int cell = t; cell < K * C; cell += 256) {
        float s = 0.f;
        for (int sp = 0; sp < SPLITS; ++sp)
            s += part[(size_t)(n * SPLITS + sp) * K * C + cell];
        int row = cell >> 7;
        vlad[cell] = s - asum_l[row] * cent[cell];
    }
    __syncthreads();
    if (t < K) {
        float ss = 0.f;
        for (int c = 0; c < C; ++c) { float v = vlad[t * C + c]; ss += v * v; }
        float ri = 1.0f / fmaxf(sqrtf(ss), 1e-12f);
        rinv_l[t] = ri;
        ssn[t] = ss * ri * ri;
    }
    __syncthreads();
    if (t == 0) {
        float g = 0.f;
        for (int k = 0; k < K; ++k) g += ssn[k];
        ginv_s = 1.0f / fmaxf(sqrtf(g), 1e-12f);
    }
    __syncthreads();
    float gi = ginv_s;
    for (int cell = t; cell < K * C; cell += 256)
        out[(size_t)n * K * C + cell] = vlad[cell] * rinv_l[cell >> 7] * gi;
}

extern "C" void kernel_launch(void* const* d_in, const int* in_sizes, int n_in,
                              void* d_out, int out_size, void* d_ws, size_t ws_size,
                              hipStream_t stream) {
    const float* x = (const float*)d_in[0];
    const float* cent = (const float*)d_in[1];
    float* out = (float*)d_out;
    char* ws = (char*)d_ws;

    float* wT              = (float*)(ws);                      // 32 KB
    float* bvec            = (float*)(ws + 32768);              // 256 B
    float* invn            = (float*)(ws + (1u << 20));         // 2 MB
    unsigned short* a_ws   = (unsigned short*)(ws + (4u << 20));// 64 MB
    float* part            = (float*)(ws + (68u << 20));        // 32 MB
    float* asum_p          = (float*)(ws + (100u << 20));       // 256 KB

    hipLaunchKernelGGL(k_prep,   dim3(1),            dim3(256), 0, stream, cent, wT, bvec);
    hipLaunchKernelGGL(k_assign, dim3(NIMG * 64),    dim3(256), 0, stream, x, wT, bvec, invn, a_ws);
    hipLaunchKernelGGL(k_vlad,   dim3(NIMG * SPLITS),dim3(256), 0, stream, x, invn, a_ws, part, asum_p);
    hipLaunchKernelGGL(k_final,  dim3(NIMG),         dim3(256), 0, stream, part, asum_p, cent, out);
}

// Round 3
// 654.607 us; speedup vs baseline: 1.0194x; 1.0194x over previous
//
#include <hip/hip_runtime.h>
#include <hip/hip_bf16.h>

// NetVLAD fused on gfx950.
// k_prep -> k_main (fused: norm + fp32 logits + softmax -> a in LDS -> bf16
// MFMA VLAD, split-s partials) -> k_reduce (parallel partial sum + rank-1
// subtract + per-(n,k) ssq) -> k_final (norms + write out).
// ws: [0,32K) wT | [32K,+256B) bvec | [1M,33M) part | [34M,+256K) asum_p |
//     [35M,+1M) vlad_red | [36M,+8K) ssq.  Needs ws_size >= 37 MB.

#define NIMG 32
#define C 128
#define S 16384
#define K 64
#define SPLITS 32
#define SPAN 512            // pixels per block
#define PXCHUNK 256         // phase granularity (== blockDim)
#define APITCH 264          // a_lds row pitch (bf16): 528 B, 16B-multiple
#define XPITCH 40           // x_lds row pitch (bf16): 80 B, 16B-multiple

typedef short bf16x8 __attribute__((ext_vector_type(8)));
typedef float f32x4 __attribute__((ext_vector_type(4)));

__device__ __forceinline__ unsigned short f2bf(float f) {
    union { __hip_bfloat16 h; unsigned short u; } v;
    v.h = __float2bfloat16(f);
    return v.u;
}

__global__ __launch_bounds__(256) void k_prep(const float* __restrict__ cent,
                                              float* __restrict__ wT,
                                              float* __restrict__ bvec) {
    int t = threadIdx.x;
    for (int idx = t; idx < C * K; idx += 256) {
        int c = idx >> 6, k = idx & 63;
        wT[idx] = 200.0f * cent[k * C + c];   // wT[c][k]
    }
    if (t < K) {
        float ss = 0.f;
        for (int c = 0; c < C; ++c) { float v = cent[t * C + c]; ss += v * v; }
        bvec[t] = -100.0f * sqrtf(ss);
    }
}

// Fused: block = (image n, s-split of 512 px). 2 chunks of 256 px.
// Phase 1: thread=pixel: ss, invn, fp32 logits, softmax, a -> LDS [k][px].
// Phase 2: 8 sub-chunks of 32 px: stage xn bf16 [c][s] -> 9 MFMA per wave.
__global__ __launch_bounds__(256, 3) void k_main(const float* __restrict__ x,
                                                 const float* __restrict__ wT,
                                                 const float* __restrict__ bvec,
                                                 float* __restrict__ part,
                                                 float* __restrict__ asum_p) {
    __shared__ unsigned short a_lds[K * APITCH];          // 33792 B
    __shared__ unsigned short x_lds[C * XPITCH];          // 10240 B
    __shared__ __align__(16) float invn_l[PXCHUNK];       // 1024 B

    int n = blockIdx.x >> 5;
    int sp = blockIdx.x & 31;
    int t = threadIdx.x, l = t & 63, w = t >> 6;
    int kw = 16 * w, l15 = l & 15, lhi = l >> 4;

    const float* xn_img = x + (size_t)n * C * S;

    f32x4 acc[8];
    f32x4 accS;
#pragma unroll
    for (int i = 0; i < 8; ++i) acc[i] = (f32x4){0.f, 0.f, 0.f, 0.f};
    accS = (f32x4){0.f, 0.f, 0.f, 0.f};

    bf16x8 ones;
#pragma unroll
    for (int i = 0; i < 8; ++i) ones[i] = (short)0x3F80;  // bf16(1.0)

    for (int ch = 0; ch < SPAN / PXCHUNK; ++ch) {
        int pxbase = sp * SPAN + ch * PXCHUNK;
        __syncthreads();   // prev chunk's MFMA reads of a_lds/invn_l are done

        // ---------------- Phase 1: assignment (thread = pixel) ----------
        const float* xp = xn_img + pxbase + t;

        // sum of squares, 4-way ILP
        float s0 = 0.f, s1 = 0.f, s2 = 0.f, s3 = 0.f;
        for (int c = 0; c < C; c += 4) {
            float v0 = xp[(size_t)(c + 0) * S];
            float v1 = xp[(size_t)(c + 1) * S];
            float v2 = xp[(size_t)(c + 2) * S];
            float v3 = xp[(size_t)(c + 3) * S];
            s0 = fmaf(v0, v0, s0); s1 = fmaf(v1, v1, s1);
            s2 = fmaf(v2, v2, s2); s3 = fmaf(v3, v3, s3);
        }
        float inv = 1.0f / fmaxf(sqrtf((s0 + s1) + (s2 + s3)), 1e-12f);
        invn_l[t] = inv;

        // logits fp32; w loads wave-uniform (scalar path)
        float lg[K];
#pragma unroll
        for (int k = 0; k < K; ++k) lg[k] = bvec[k];
        for (int c = 0; c < C; c += 4) {
            float x0 = xp[(size_t)(c + 0) * S] * inv;
            float x1 = xp[(size_t)(c + 1) * S] * inv;
            float x2 = xp[(size_t)(c + 2) * S] * inv;
            float x3 = xp[(size_t)(c + 3) * S] * inv;
#pragma unroll
            for (int cc = 0; cc < 4; ++cc) {
                float xnc = (cc == 0) ? x0 : (cc == 1) ? x1 : (cc == 2) ? x2 : x3;
                const float4* wrow = (const float4*)(wT + (c + cc) * K);
#pragma unroll
                for (int k4 = 0; k4 < K / 4; ++k4) {
                    float4 wv = wrow[k4];
                    lg[4 * k4 + 0] = fmaf(wv.x, xnc, lg[4 * k4 + 0]);
                    lg[4 * k4 + 1] = fmaf(wv.y, xnc, lg[4 * k4 + 1]);
                    lg[4 * k4 + 2] = fmaf(wv.z, xnc, lg[4 * k4 + 2]);
                    lg[4 * k4 + 3] = fmaf(wv.w, xnc, lg[4 * k4 + 3]);
                }
            }
        }

        // softmax over K in registers
        float m = lg[0];
#pragma unroll
        for (int k = 1; k < K; ++k) m = fmaxf(m, lg[k]);
        float sum = 0.f;
#pragma unroll
        for (int k = 0; k < K; ++k) { lg[k] = __expf(lg[k] - m); sum += lg[k]; }
        float rs = 1.0f / sum;

        // a -> LDS [k][px]: fixed k across lanes => contiguous 2B, no conflicts
#pragma unroll
        for (int k = 0; k < K; ++k) a_lds[k * APITCH + t] = f2bf(lg[k] * rs);

        // ---------------- Phase 2: VLAD MFMA ----------------------------
        for (int sc = 0; sc < PXCHUNK / 32; ++sc) {
            __syncthreads();   // sc=0: a_lds/invn_l ready; sc>0: x_lds free
            {   // stage xn bf16 [c][32]: c = t>>1, 16 px per thread
                int c = t >> 1, half = t & 1;
                int sg = pxbase + 32 * sc + 16 * half;
                const float4* xsrc = (const float4*)(xn_img + (size_t)c * S + sg);
                const float4* isrc = (const float4*)(&invn_l[32 * sc + 16 * half]);
                unsigned int uu[8];
#pragma unroll
                for (int q = 0; q < 4; ++q) {
                    float4 xv = xsrc[q];
                    float4 iv = isrc[q];
                    unsigned short b0 = f2bf(xv.x * iv.x), b1 = f2bf(xv.y * iv.y);
                    unsigned short b2 = f2bf(xv.z * iv.z), b3 = f2bf(xv.w * iv.w);
                    uu[2 * q]     = (unsigned int)b0 | ((unsigned int)b1 << 16);
                    uu[2 * q + 1] = (unsigned int)b2 | ((unsigned int)b3 << 16);
                }
                uint4 w0 = {uu[0], uu[1], uu[2], uu[3]};
                uint4 w1 = {uu[4], uu[5], uu[6], uu[7]};
                *(uint4*)(&x_lds[c * XPITCH + 16 * half])     = w0;
                *(uint4*)(&x_lds[c * XPITCH + 16 * half + 8]) = w1;
            }
            __syncthreads();

            bf16x8 af = *(const bf16x8*)(&a_lds[(kw + l15) * APITCH + 32 * sc + 8 * lhi]);
#pragma unroll
            for (int nt = 0; nt < 8; ++nt) {
                bf16x8 bfv = *(const bf16x8*)(&x_lds[(16 * nt + l15) * XPITCH + 8 * lhi]);
                acc[nt] = __builtin_amdgcn_mfma_f32_16x16x32_bf16(af, bfv, acc[nt], 0, 0, 0);
            }
            accS = __builtin_amdgcn_mfma_f32_16x16x32_bf16(af, ones, accS, 0, 0, 0);
        }
    }

    // Partials. D: col = l15 (+16*nt), row = kw + 4*lhi + j.
    size_t pbase = (size_t)(n * SPLITS + sp) * K * C;
#pragma unroll
    for (int nt = 0; nt < 8; ++nt) {
#pragma unroll
        for (int j = 0; j < 4; ++j) {
            int row = kw + 4 * lhi + j;
            int col = 16 * nt + l15;
            part[pbase + (size_t)row * C + col] = acc[nt][j];
        }
    }
    if (l15 == 0) {
        int rb = kw + 4 * lhi;
#pragma unroll
        for (int j = 0; j < 4; ++j)
            asum_p[(size_t)(n * SPLITS + sp) * K + rb + j] = accS[j];
    }
}

// Parallel partial reduce + rank-1 subtract + per-(n,k) ssq.
// Grid 256 blocks: 8 per image; thread owns one float4 (4 cells, same k-row).
__global__ __launch_bounds__(256) void k_reduce(const float* __restrict__ part,
                                                const float* __restrict__ asum_p,
                                                const float* __restrict__ cent,
                                                float* __restrict__ vlad_red,
                                                float* __restrict__ ssq) {
    __shared__ float asum_l[K];
    int n = blockIdx.x >> 3;
    int cg = blockIdx.x & 7;
    int t = threadIdx.x;

    if (t < K) {
        float s = 0.f;
        for (int sp = 0; sp < SPLITS; ++sp) s += asum_p[(size_t)(n * SPLITS + sp) * K + t];
        asum_l[t] = s;
    }
    __syncthreads();

    int cell4 = cg * 256 + t;        // float4 index within image, k = cell>>7
    int k = (cell4 * 4) >> 7;        // = 8*cg + (t>>5): 32-thread groups per row
    float4 acc = {0.f, 0.f, 0.f, 0.f};
    for (int sp = 0; sp < SPLITS; ++sp) {
        const float4* p = (const float4*)(part + (size_t)(n * SPLITS + sp) * K * C);
        float4 v = p[cell4];
        acc.x += v.x; acc.y += v.y; acc.z += v.z; acc.w += v.w;
    }
    float am = asum_l[k];
    float4 cv = ((const float4*)cent)[cell4];
    acc.x -= am * cv.x; acc.y -= am * cv.y;
    acc.z -= am * cv.z; acc.w -= am * cv.w;
    ((float4*)vlad_red)[(size_t)n * 2048 + cell4] = acc;

    float sq = acc.x * acc.x + acc.y * acc.y + acc.z * acc.z + acc.w * acc.w;
#pragma unroll
    for (int st = 16; st >= 1; st >>= 1) sq += __shfl_xor(sq, st);
    if ((t & 31) == 0) ssq[n * K + k] = sq;
}

__global__ __launch_bounds__(256) void k_final(const float* __restrict__ vlad_red,
                                               const float* __restrict__ ssq,
                                               float* __restrict__ out) {
    __shared__ float ri_l[K];
    __shared__ float ssn[K];
    __shared__ float gi_s;
    int n = blockIdx.x, t = threadIdx.x;

    if (t < K) {
        float ss = ssq[n * K + t];
        float ri = 1.0f / fmaxf(sqrtf(ss), 1e-12f);
        ri_l[t] = ri;
        ssn[t] = ss * ri * ri;
    }
    __syncthreads();
    if (t == 0) {
        float g = 0.f;
        for (int k = 0; k < K; ++k) g += ssn[k];
        gi_s = 1.0f / fmaxf(sqrtf(g), 1e-12f);
    }
    __syncthreads();
    float gi = gi_s;
    for (int c4 = t; c4 < 2048; c4 += 256) {
        float4 v = ((const float4*)vlad_red)[(size_t)n * 2048 + c4];
        float r = ri_l[c4 >> 5] * gi;
        v.x *= r; v.y *= r; v.z *= r; v.w *= r;
        ((float4*)out)[(size_t)n * 2048 + c4] = v;
    }
}

extern "C" void kernel_launch(void* const* d_in, const int* in_sizes, int n_in,
                              void* d_out, int out_size, void* d_ws, size_t ws_size,
                              hipStream_t stream) {
    const float* x = (const float*)d_in[0];
    const float* cent = (const float*)d_in[1];
    float* out = (float*)d_out;
    char* ws = (char*)d_ws;

    float* wT       = (float*)(ws);                  // 32 KB
    float* bvec     = (float*)(ws + 32768);          // 256 B
    float* part     = (float*)(ws + (1u << 20));     // 32 MB
    float* asum_p   = (float*)(ws + (34u << 20));    // 256 KB
    float* vlad_red = (float*)(ws + (35u << 20));    // 1 MB
    float* ssq      = (float*)(ws + (36u << 20));    // 8 KB

    hipLaunchKernelGGL(k_prep,   dim3(1),              dim3(256), 0, stream, cent, wT, bvec);
    hipLaunchKernelGGL(k_main,   dim3(NIMG * SPLITS),  dim3(256), 0, stream, x, wT, bvec, part, asum_p);
    hipLaunchKernelGGL(k_reduce, dim3(NIMG * 8),       dim3(256), 0, stream, part, asum_p, cent, vlad_red, ssq);
    hipLaunchKernelGGL(k_final,  dim3(NIMG),           dim3(256), 0, stream, vlad_red, ssq, out);
}

// Round 4
// 425.834 us; speedup vs baseline: 1.5670x; 1.5372x over previous
//
#include <hip/hip_runtime.h>
#include <hip/hip_bf16.h>

// NetVLAD fused, MFMA-everything, on gfx950.
// k_prep (bvec) -> k_main (stage x hi/lo -> 3-pass split-bf16 MFMA logits ->
// reg softmax -> a'=a*invn bf16 -> VLAD MFMA, split-s partials) ->
// k_reduce -> k_final.
// ws: [0,+256B) bvec | [1M,33M) part | [34M,+256K) asum_p | [35M,+1M) vlad_red
//     | [36M,+8K) ssq.  Needs ws_size >= 37 MB.

#define NIMG 32
#define C 128
#define S 16384
#define K 64
#define SPLITS 32
#define SPAN 512            // pixels per block
#define PXC 64              // pixels per chunk
#define XTP 136             // xT row pitch (bf16 elems): 272 B (16B-mult, 68 dw)
#define AP 72               // a_lds row pitch (bf16): 144 B
#define XP 40               // x_lds row pitch (bf16): 80 B

typedef short bf16x8 __attribute__((ext_vector_type(8)));
typedef float f32x4 __attribute__((ext_vector_type(4)));

__device__ __forceinline__ unsigned short f2bf(float f) {
    union { __hip_bfloat16 h; unsigned short u; } v;
    v.h = __float2bfloat16(f);
    return v.u;
}
__device__ __forceinline__ float bf2f(unsigned short u) {
    return __uint_as_float(((unsigned int)u) << 16);
}

__global__ __launch_bounds__(256) void k_prep(const float* __restrict__ cent,
                                              float* __restrict__ bvec) {
    int t = threadIdx.x;
    if (t < K) {
        float ss = 0.f;
        for (int c = 0; c < C; ++c) { float v = cent[t * C + c]; ss += v * v; }
        bvec[t] = -100.0f * sqrtf(ss);
    }
}

// LDS carve (bytes):
//   xTh      [64][XTP] bf16   @ 0      , 17408
//   xTl/x_lds(aliased)        @ 17408  , 17408  (x_lds needs 128*40*2=10240)
//   a_lds    [64][AP] bf16    @ 34816  , 9216
//   ssq_part [4][64] f32      @ 44032  , 1024
//   redA     [64][4] f32      @ 45056  , 1024
//   redB     [64][4] f32      @ 46080  , 1024
#define SMEM_BYTES 47104

__global__ __launch_bounds__(256, 3) void k_main(const float* __restrict__ x,
                                                 const float* __restrict__ cent,
                                                 const float* __restrict__ bvec,
                                                 float* __restrict__ part,
                                                 float* __restrict__ asum_p) {
    __shared__ __align__(16) char smem[SMEM_BYTES];
    unsigned short* xTh   = (unsigned short*)(smem);
    unsigned short* xTl   = (unsigned short*)(smem + 17408);
    unsigned short* x_lds = (unsigned short*)(smem + 17408);   // aliased (phase 4)
    unsigned short* a_lds = (unsigned short*)(smem + 34816);
    float* ssq_part       = (float*)(smem + 44032);
    float* redA           = (float*)(smem + 45056);
    float* redB           = (float*)(smem + 46080);

    int n = blockIdx.x >> 5;
    int sp = blockIdx.x & 31;
    int t = threadIdx.x, l = t & 63, w = t >> 6;
    int kw = 16 * w, l15 = l & 15, lhi = l >> 4;

    const float* xn_img = x + (size_t)n * C * S;

    // ---- w fragments (hi/lo) in registers, once ----
    bf16x8 wh[4], wl[4];
#pragma unroll
    for (int cs = 0; cs < 4; ++cs) {
        const float* wrow = cent + (kw + l15) * C + cs * 32 + 8 * lhi;
#pragma unroll
        for (int e = 0; e < 8; ++e) {
            float wv = 200.0f * wrow[e];
            unsigned short h = f2bf(wv);
            wh[cs][e] = (short)h;
            wl[cs][e] = (short)f2bf(wv - bf2f(h));
        }
    }
    float bias[4];
#pragma unroll
    for (int j = 0; j < 4; ++j) bias[j] = bvec[kw + 4 * lhi + j];

    f32x4 acc[8];
#pragma unroll
    for (int i = 0; i < 8; ++i) acc[i] = (f32x4){0.f, 0.f, 0.f, 0.f};
    float asumacc[4] = {0.f, 0.f, 0.f, 0.f};

    for (int ch = 0; ch < SPAN / PXC; ++ch) {
        int pxbase = sp * SPAN + ch * PXC;
        __syncthreads();   // prev chunk phase-4 reads of aliased x_lds done

        // ---------- Phase 1: stage xT hi/lo + ssq ----------
        {
            int px = t & 63, cq = t >> 6;
            const float* xcol = xn_img + (size_t)(cq * 32) * S + pxbase + px;
            float sa = 0.f, sb = 0.f;
#pragma unroll
            for (int u = 0; u < 4; ++u) {
                unsigned int bh[4], bl[4];
#pragma unroll
                for (int e = 0; e < 4; ++e) {
                    float v0 = xcol[(size_t)(u * 8 + 2 * e) * S];
                    float v1 = xcol[(size_t)(u * 8 + 2 * e + 1) * S];
                    sa = fmaf(v0, v0, sa);
                    sb = fmaf(v1, v1, sb);
                    unsigned short h0 = f2bf(v0), h1 = f2bf(v1);
                    unsigned short l0 = f2bf(v0 - bf2f(h0));
                    unsigned short l1 = f2bf(v1 - bf2f(h1));
                    bh[e] = (unsigned int)h0 | ((unsigned int)h1 << 16);
                    bl[e] = (unsigned int)l0 | ((unsigned int)l1 << 16);
                }
                int c0 = cq * 32 + u * 8;
                uint4 vh = {bh[0], bh[1], bh[2], bh[3]};
                uint4 vl = {bl[0], bl[1], bl[2], bl[3]};
                *(uint4*)(&xTh[px * XTP + c0]) = vh;
                *(uint4*)(&xTl[px * XTP + c0]) = vl;
            }
            ssq_part[cq * 64 + px] = sa + sb;
        }
        __syncthreads();   // A1: xT + ssq ready

        // ---------- Phase 2: logits MFMA (3-pass split bf16) ----------
        f32x4 lgacc[4];
#pragma unroll
        for (int t4 = 0; t4 < 4; ++t4) lgacc[t4] = (f32x4){0.f, 0.f, 0.f, 0.f};
#pragma unroll
        for (int t4 = 0; t4 < 4; ++t4) {
#pragma unroll
            for (int cs = 0; cs < 4; ++cs) {
                int boff = (16 * t4 + l15) * XTP + cs * 32 + 8 * lhi;
                bf16x8 bh = *(const bf16x8*)(&xTh[boff]);
                bf16x8 bl = *(const bf16x8*)(&xTl[boff]);
                lgacc[t4] = __builtin_amdgcn_mfma_f32_16x16x32_bf16(wh[cs], bh, lgacc[t4], 0, 0, 0);
                lgacc[t4] = __builtin_amdgcn_mfma_f32_16x16x32_bf16(wh[cs], bl, lgacc[t4], 0, 0, 0);
                lgacc[t4] = __builtin_amdgcn_mfma_f32_16x16x32_bf16(wl[cs], bh, lgacc[t4], 0, 0, 0);
            }
        }

        // ---------- Phase 3: softmax (regs + shfl + 1KB LDS) ----------
        // lane holds lgacc[t4][j] : px = 16*t4 + l15, k = kw + 4*lhi + j
        float invt[4];
#pragma unroll
        for (int t4 = 0; t4 < 4; ++t4) {
            int px = 16 * t4 + l15;
            float s = ssq_part[px] + ssq_part[64 + px] + ssq_part[128 + px] + ssq_part[192 + px];
            invt[t4] = 1.0f / fmaxf(sqrtf(s), 1e-12f);
        }
        float lg[4][4];
        float pmax[4];
#pragma unroll
        for (int t4 = 0; t4 < 4; ++t4) {
            float m = -3.4e38f;
#pragma unroll
            for (int j = 0; j < 4; ++j) {
                lg[t4][j] = fmaf(lgacc[t4][j], invt[t4], bias[j]);
                m = fmaxf(m, lg[t4][j]);
            }
            pmax[t4] = m;
        }
#pragma unroll
        for (int t4 = 0; t4 < 4; ++t4) {
            pmax[t4] = fmaxf(pmax[t4], __shfl_xor(pmax[t4], 16));
            pmax[t4] = fmaxf(pmax[t4], __shfl_xor(pmax[t4], 32));
        }
        if (l < 16) {
#pragma unroll
            for (int t4 = 0; t4 < 4; ++t4) redA[(16 * t4 + l15) * 4 + w] = pmax[t4];
        }
        __syncthreads();   // B
        float psum[4];
#pragma unroll
        for (int t4 = 0; t4 < 4; ++t4) {
            float4 mv = *(const float4*)(&redA[(16 * t4 + l15) * 4]);
            float m = fmaxf(fmaxf(mv.x, mv.y), fmaxf(mv.z, mv.w));
            float s = 0.f;
#pragma unroll
            for (int j = 0; j < 4; ++j) {
                float p = __expf(lg[t4][j] - m);
                lg[t4][j] = p;
                s += p;
            }
            psum[t4] = s;
        }
#pragma unroll
        for (int t4 = 0; t4 < 4; ++t4) {
            psum[t4] += __shfl_xor(psum[t4], 16);
            psum[t4] += __shfl_xor(psum[t4], 32);
        }
        if (l < 16) {
#pragma unroll
            for (int t4 = 0; t4 < 4; ++t4) redB[(16 * t4 + l15) * 4 + w] = psum[t4];
        }
        __syncthreads();   // C
#pragma unroll
        for (int t4 = 0; t4 < 4; ++t4) {
            float4 sv = *(const float4*)(&redB[(16 * t4 + l15) * 4]);
            float rs = 1.0f / (sv.x + sv.y + sv.z + sv.w);
            float inv = invt[t4];
#pragma unroll
            for (int j = 0; j < 4; ++j) {
                float a = lg[t4][j] * rs;
                asumacc[j] += a;
                a_lds[(kw + 4 * lhi + j) * AP + 16 * t4 + l15] = f2bf(a * inv);
            }
        }

        // ---------- Phase 4: VLAD MFMA (a' x raw-x-bf16) ----------
        for (int sc = 0; sc < 2; ++sc) {
            __syncthreads();   // sc=0: a_lds ready + aliased region free; sc=1: x_lds free
            {
                int c = t >> 1, half = t & 1;
                const float4* xsrc = (const float4*)(xn_img + (size_t)c * S + pxbase + 32 * sc + 16 * half);
                unsigned int uu[8];
#pragma unroll
                for (int q = 0; q < 4; ++q) {
                    float4 xv = xsrc[q];
                    unsigned short b0 = f2bf(xv.x), b1 = f2bf(xv.y);
                    unsigned short b2 = f2bf(xv.z), b3 = f2bf(xv.w);
                    uu[2 * q]     = (unsigned int)b0 | ((unsigned int)b1 << 16);
                    uu[2 * q + 1] = (unsigned int)b2 | ((unsigned int)b3 << 16);
                }
                uint4 w0 = {uu[0], uu[1], uu[2], uu[3]};
                uint4 w1 = {uu[4], uu[5], uu[6], uu[7]};
                *(uint4*)(&x_lds[c * XP + 16 * half])     = w0;
                *(uint4*)(&x_lds[c * XP + 16 * half + 8]) = w1;
            }
            __syncthreads();
            bf16x8 af = *(const bf16x8*)(&a_lds[(kw + l15) * AP + 32 * sc + 8 * lhi]);
#pragma unroll
            for (int nt = 0; nt < 8; ++nt) {
                bf16x8 bfv = *(const bf16x8*)(&x_lds[(16 * nt + l15) * XP + 8 * lhi]);
                acc[nt] = __builtin_amdgcn_mfma_f32_16x16x32_bf16(af, bfv, acc[nt], 0, 0, 0);
            }
        }
    }

    // ---------- epilogue: partials + asum ----------
    size_t pbase = (size_t)(n * SPLITS + sp) * K * C;
#pragma unroll
    for (int nt = 0; nt < 8; ++nt) {
#pragma unroll
        for (int j = 0; j < 4; ++j) {
            int row = kw + 4 * lhi + j;
            int col = 16 * nt + l15;
            part[pbase + (size_t)row * C + col] = acc[nt][j];
        }
    }
#pragma unroll
    for (int j = 0; j < 4; ++j) {
        float v = asumacc[j];
        v += __shfl_xor(v, 1);
        v += __shfl_xor(v, 2);
        v += __shfl_xor(v, 4);
        v += __shfl_xor(v, 8);
        if (l15 == 0)
            asum_p[(size_t)(n * SPLITS + sp) * K + kw + 4 * lhi + j] = v;
    }
}

// Parallel partial reduce + rank-1 subtract + per-(n,k) ssq.
__global__ __launch_bounds__(256) void k_reduce(const float* __restrict__ part,
                                                const float* __restrict__ asum_p,
                                                const float* __restrict__ cent,
                                                float* __restrict__ vlad_red,
                                                float* __restrict__ ssq) {
    __shared__ float asum_l[K];
    int n = blockIdx.x >> 3;
    int cg = blockIdx.x & 7;
    int t = threadIdx.x;

    if (t < K) {
        float s = 0.f;
        for (int sp = 0; sp < SPLITS; ++sp) s += asum_p[(size_t)(n * SPLITS + sp) * K + t];
        asum_l[t] = s;
    }
    __syncthreads();

    int cell4 = cg * 256 + t;
    int k = (cell4 * 4) >> 7;
    float4 acc = {0.f, 0.f, 0.f, 0.f};
    for (int sp = 0; sp < SPLITS; ++sp) {
        const float4* p = (const float4*)(part + (size_t)(n * SPLITS + sp) * K * C);
        float4 v = p[cell4];
        acc.x += v.x; acc.y += v.y; acc.z += v.z; acc.w += v.w;
    }
    float am = asum_l[k];
    const float4 cv = ((const float4*)cent)[cell4];
    acc.x -= am * cv.x; acc.y -= am * cv.y;
    acc.z -= am * cv.z; acc.w -= am * cv.w;
    ((float4*)vlad_red)[(size_t)n * 2048 + cell4] = acc;

    float sq = acc.x * acc.x + acc.y * acc.y + acc.z * acc.z + acc.w * acc.w;
#pragma unroll
    for (int st = 16; st >= 1; st >>= 1) sq += __shfl_xor(sq, st);
    if ((t & 31) == 0) ssq[n * K + k] = sq;
}

__global__ __launch_bounds__(256) void k_final(const float* __restrict__ vlad_red,
                                               const float* __restrict__ ssq,
                                               float* __restrict__ out) {
    __shared__ float ri_l[K];
    __shared__ float ssn[K];
    __shared__ float gi_s;
    int n = blockIdx.x, t = threadIdx.x;

    if (t < K) {
        float ss = ssq[n * K + t];
        float ri = 1.0f / fmaxf(sqrtf(ss), 1e-12f);
        ri_l[t] = ri;
        ssn[t] = ss * ri * ri;
    }
    __syncthreads();
    if (t == 0) {
        float g = 0.f;
        for (int k = 0; k < K; ++k) g += ssn[k];
        gi_s = 1.0f / fmaxf(sqrtf(g), 1e-12f);
    }
    __syncthreads();
    float gi = gi_s;
    for (int c4 = t; c4 < 2048; c4 += 256) {
        float4 v = ((const float4*)vlad_red)[(size_t)n * 2048 + c4];
        float r = ri_l[c4 >> 5] * gi;
        v.x *= r; v.y *= r; v.z *= r; v.w *= r;
        ((float4*)out)[(size_t)n * 2048 + c4] = v;
    }
}

extern "C" void kernel_launch(void* const* d_in, const int* in_sizes, int n_in,
                              void* d_out, int out_size, void* d_ws, size_t ws_size,
                              hipStream_t stream) {
    const float* x = (const float*)d_in[0];
    const float* cent = (const float*)d_in[1];
    float* out = (float*)d_out;
    char* ws = (char*)d_ws;

    float* bvec     = (float*)(ws);                  // 256 B
    float* part     = (float*)(ws + (1u << 20));     // 32 MB
    float* asum_p   = (float*)(ws + (34u << 20));    // 256 KB
    float* vlad_red = (float*)(ws + (35u << 20));    // 1 MB
    float* ssq      = (float*)(ws + (36u << 20));    // 8 KB

    hipLaunchKernelGGL(k_prep,   dim3(1),             dim3(256), 0, stream, cent, bvec);
    hipLaunchKernelGGL(k_main,   dim3(NIMG * SPLITS), dim3(256), 0, stream, x, cent, bvec, part, asum_p);
    hipLaunchKernelGGL(k_reduce, dim3(NIMG * 8),      dim3(256), 0, stream, part, asum_p, cent, vlad_red, ssq);
    hipLaunchKernelGGL(k_final,  dim3(NIMG),          dim3(256), 0, stream, vlad_red, ssq, out);
}